// Round 18
// baseline (1328.658 us; speedup 1.0000x reference)
//
#include <hip/hip_runtime.h>
#include <hip/hip_bf16.h>

// GIN 4-layer forward, round 18: tail work. agg_tx neighbor loop 4-deep
// unrolled (batch idx batch-loaded, 4 independent row chains); moment_k at
// 512 blocks (fills all CUs). fused_k (64-tile, 2 blocks/CU) unchanged.

typedef __attribute__((ext_vector_type(8))) short bf16x8;
typedef __attribute__((ext_vector_type(4))) float f32x4;

#define MOMB 512

__device__ __forceinline__ unsigned short f2b(float x){
    __hip_bfloat16 h = __float2bfloat16(x);
    return *reinterpret_cast<unsigned short*>(&h);
}
__device__ __forceinline__ float b2f(unsigned short u){
    __hip_bfloat16 h;
    *reinterpret_cast<unsigned short*>(&h) = u;
    return __bfloat162float(h);
}
__device__ __forceinline__ float selu_f(float x){
    const float sc = 1.0507009873554805f, al = 1.6732632423543772f;
    return x > 0.f ? sc * x : sc * al * (__expf(x) - 1.f);
}

// ---------------- CSR build ----------------
__global__ void count_kernel(const int* __restrict__ dst, int* __restrict__ counts, int E){
    int e = blockIdx.x * 256 + threadIdx.x;
    if (e < E) atomicAdd(&counts[dst[e]], 1);
}

__global__ void cnt_bs_kernel(const int* __restrict__ batch, float* __restrict__ cnt, int N){
    __shared__ int sb[257];
    int g = threadIdx.x;
    int lo = 0, hi = N;
    while (lo < hi){ int mid = (lo + hi) >> 1; if (batch[mid] < g) lo = mid + 1; else hi = mid; }
    sb[g] = lo;
    if (g == 0) sb[256] = N;
    __syncthreads();
    cnt[g] = fmaxf((float)(sb[g + 1] - sb[g]), 1.f);
}

__global__ __launch_bounds__(1024) void scan_kernel(const int* __restrict__ counts,
                                                    int* __restrict__ row_ptr, int N){
    __shared__ int wsum[16];
    __shared__ int wpre[16];
    __shared__ int s_total;
    __shared__ int s_running;
    int tid = threadIdx.x;
    int lane = tid & 63, wid = tid >> 6;
    if (tid == 0) s_running = 0;
    __syncthreads();
    for (int base = 0; base < N; base += 4096){
        int idx0 = base + tid * 4;
        int v[4];
        #pragma unroll
        for (int j = 0; j < 4; j++) v[j] = (idx0 + j < N) ? counts[idx0 + j] : 0;
        int tsum = v[0] + v[1] + v[2] + v[3];
        int x = tsum;
        #pragma unroll
        for (int off = 1; off < 64; off <<= 1){
            int y = __shfl_up(x, off, 64);
            if (lane >= off) x += y;
        }
        if (lane == 63) wsum[wid] = x;
        __syncthreads();
        if (wid == 0 && lane < 16){
            int w = wsum[lane];
            int xx = w;
            #pragma unroll
            for (int off = 1; off < 16; off <<= 1){
                int y = __shfl_up(xx, off, 64);
                if (lane >= off) xx += y;
            }
            wpre[lane] = xx - w;
            if (lane == 15) s_total = xx;
        }
        __syncthreads();
        int run = s_running + wpre[wid] + (x - tsum);
        #pragma unroll
        for (int j = 0; j < 4; j++){
            if (idx0 + j < N) row_ptr[idx0 + j] = run;
            run += v[j];
        }
        __syncthreads();
        if (tid == 0) s_running += s_total;
        __syncthreads();
    }
    if (tid == 0) row_ptr[N] = s_running;
}

__global__ void fill_kernel(const int* __restrict__ ei, const int* __restrict__ row_ptr,
                            int* __restrict__ fill, int* __restrict__ colv, int E){
    int e = blockIdx.x * 256 + threadIdx.x;
    if (e < E){
        int s = ei[e];
        int d = ei[E + e];
        int pos = atomicAdd(&fill[d], 1);
        colv[row_ptr[d] + pos] = s;
    }
}

// ------------- weight pre-pack: f32 -> bf16 hi/lo fragments -------------
__global__ void pack_kernel(const float* __restrict__ W1, const float* __restrict__ W2,
                            unsigned short* __restrict__ W1p, unsigned short* __restrict__ W2p){
    int t = blockIdx.x * 256 + threadIdx.x;   // 65536 total
    int which = t >> 15;
    int u = t & 32767;
    int lane = u & 63; u >>= 6;
    int nf = u & 3; u >>= 2;
    int wc = u & 1; u >>= 1;
    int kk = u & 3; u >>= 2;
    int c = u & 3; u >>= 2;
    int l = u;
    int col = wc * 64 + nf * 16 + (lane & 15);
    int kbase = kk * 32 + (lane >> 4) * 8;
    size_t ob = ((((((size_t)(l * 4 + c) * 4 + kk) * 2 + wc) * 4 + nf) * 2) * 512) + lane * 8;
    unsigned short* dst = which == 0 ? W1p : W2p;
    #pragma unroll
    for (int j = 0; j < 8; j++){
        int k = kbase + j;
        float wv = which == 0 ? W1[((size_t)(l * 512) + c * 128 + col) * 128 + k]
                              : W2[((size_t)(l * 128) + col) * 512 + c * 128 + k];
        unsigned short hi = f2b(wv);
        unsigned short lo = f2b(wv - b2f(hi));
        dst[ob + j] = hi;
        dst[ob + 512 + j] = lo;
    }
}

// ------- layer-0 aggregation (x input, no transform) -> z0 fragments -------
__global__ __launch_bounds__(256) void agg_split_kernel(
    const float* __restrict__ h, const int* __restrict__ row_ptr,
    const int* __restrict__ colv,
    unsigned short* __restrict__ zhi, unsigned short* __restrict__ zlo, int N)
{
    int t = blockIdx.x * 256 + threadIdx.x;
    int i = t >> 5;
    if (i >= N) return;
    int vo = (t & 31);
    const float4* hv = reinterpret_cast<const float4*>(h);
    int p0 = row_ptr[i], p1 = row_ptr[i + 1];
    float4 acc = hv[(size_t)i * 32 + vo];
    int p = p0;
    for (; p + 4 <= p1; p += 4){
        int s0 = colv[p], s1 = colv[p + 1], s2 = colv[p + 2], s3 = colv[p + 3];
        float4 a = hv[(size_t)s0 * 32 + vo];
        float4 b = hv[(size_t)s1 * 32 + vo];
        float4 c = hv[(size_t)s2 * 32 + vo];
        float4 d = hv[(size_t)s3 * 32 + vo];
        acc.x += (a.x + b.x) + (c.x + d.x);
        acc.y += (a.y + b.y) + (c.y + d.y);
        acc.z += (a.z + b.z) + (c.z + d.z);
        acc.w += (a.w + b.w) + (c.w + d.w);
    }
    for (; p < p1; p++){
        float4 a = hv[(size_t)colv[p] * 32 + vo];
        acc.x += a.x; acc.y += a.y; acc.z += a.z; acc.w += a.w;
    }
    float vals[4] = {acc.x, acc.y, acc.z, acc.w};
    unsigned int h01, h23, l01, l23;
    {
        unsigned short hh[4], ll[4];
        #pragma unroll
        for (int j = 0; j < 4; j++){
            hh[j] = f2b(vals[j]);
            ll[j] = f2b(vals[j] - b2f(hh[j]));
        }
        h01 = (unsigned int)hh[0] | ((unsigned int)hh[1] << 16);
        h23 = (unsigned int)hh[2] | ((unsigned int)hh[3] << 16);
        l01 = (unsigned int)ll[0] | ((unsigned int)ll[1] << 16);
        l23 = (unsigned int)ll[2] | ((unsigned int)ll[3] << 16);
    }
    int kk = vo >> 3, kg = (vo >> 1) & 3, half = vo & 1;
    size_t fo = ((size_t)(i >> 4) * 4 + kk) * 512 + (kg * 16 + (i & 15)) * 8 + half * 4;
    *reinterpret_cast<uint2*>(zhi + fo) = make_uint2(h01, h23);
    *reinterpret_cast<uint2*>(zlo + fo) = make_uint2(l01, l23);
}

// ------- layers 1..3 aggregation: gather raw z2, apply GN+SELU per row,
//         pool own-row values, write z0 fragments. 4-deep unrolled. -------
__global__ __launch_bounds__(256) void agg_tx_kernel(
    const float* __restrict__ z2, const int* __restrict__ row_ptr,
    const int* __restrict__ colv, const int* __restrict__ batch,
    const float* __restrict__ scale, const float* __restrict__ shift,
    unsigned short* __restrict__ zhi, unsigned short* __restrict__ zlo,
    float* __restrict__ pool, int lpool, int N)
{
    __shared__ float pbuf[8][128];
    __shared__ int s_g[8];
    int tid = threadIdx.x;
    int t = blockIdx.x * 256 + tid;
    int i = t >> 5;
    int vo = t & 31;
    int il = tid >> 5;
    if (vo == 0) s_g[il] = (i < N) ? batch[i] : -1;
    const float4* hv = reinterpret_cast<const float4*>(z2);
    float4 acc = make_float4(0.f, 0.f, 0.f, 0.f);
    if (i < N){
        int gi = batch[i];
        float4 v  = hv[(size_t)i * 32 + vo];
        float4 c4 = *reinterpret_cast<const float4*>(&scale[gi * 128 + vo * 4]);
        float4 s4 = *reinterpret_cast<const float4*>(&shift[gi * 128 + vo * 4]);
        acc.x = selu_f(fmaf(v.x, c4.x, s4.x));
        acc.y = selu_f(fmaf(v.y, c4.y, s4.y));
        acc.z = selu_f(fmaf(v.z, c4.z, s4.z));
        acc.w = selu_f(fmaf(v.w, c4.w, s4.w));
        pbuf[il][vo * 4 + 0] = acc.x;
        pbuf[il][vo * 4 + 1] = acc.y;
        pbuf[il][vo * 4 + 2] = acc.z;
        pbuf[il][vo * 4 + 3] = acc.w;
    }
    __syncthreads();
    if (tid < 128){
        float s = 0.f; int rg = -2;
        #pragma unroll
        for (int k = 0; k < 8; k++){
            int g = s_g[k];
            if (g < 0) continue;
            if (g != rg){
                if (rg >= 0) atomicAdd(&pool[rg * 512 + lpool * 128 + tid], s);
                s = 0.f; rg = g;
            }
            s += pbuf[k][tid];
        }
        if (rg >= 0) atomicAdd(&pool[rg * 512 + lpool * 128 + tid], s);
    }
    if (i >= N) return;

    int p0 = row_ptr[i], p1 = row_ptr[i + 1];
    int p = p0;
    for (; p + 4 <= p1; p += 4){
        int s0 = colv[p], s1 = colv[p + 1], s2 = colv[p + 2], s3 = colv[p + 3];
        int g0 = batch[s0], g1 = batch[s1], g2 = batch[s2], g3 = batch[s3];
        float4 v0 = hv[(size_t)s0 * 32 + vo];
        float4 v1 = hv[(size_t)s1 * 32 + vo];
        float4 v2 = hv[(size_t)s2 * 32 + vo];
        float4 v3 = hv[(size_t)s3 * 32 + vo];
        float4 c0 = *reinterpret_cast<const float4*>(&scale[g0 * 128 + vo * 4]);
        float4 h0 = *reinterpret_cast<const float4*>(&shift[g0 * 128 + vo * 4]);
        float4 c1 = *reinterpret_cast<const float4*>(&scale[g1 * 128 + vo * 4]);
        float4 h1 = *reinterpret_cast<const float4*>(&shift[g1 * 128 + vo * 4]);
        float4 c2 = *reinterpret_cast<const float4*>(&scale[g2 * 128 + vo * 4]);
        float4 h2 = *reinterpret_cast<const float4*>(&shift[g2 * 128 + vo * 4]);
        float4 c3 = *reinterpret_cast<const float4*>(&scale[g3 * 128 + vo * 4]);
        float4 h3 = *reinterpret_cast<const float4*>(&shift[g3 * 128 + vo * 4]);
        acc.x += (selu_f(fmaf(v0.x, c0.x, h0.x)) + selu_f(fmaf(v1.x, c1.x, h1.x)))
               + (selu_f(fmaf(v2.x, c2.x, h2.x)) + selu_f(fmaf(v3.x, c3.x, h3.x)));
        acc.y += (selu_f(fmaf(v0.y, c0.y, h0.y)) + selu_f(fmaf(v1.y, c1.y, h1.y)))
               + (selu_f(fmaf(v2.y, c2.y, h2.y)) + selu_f(fmaf(v3.y, c3.y, h3.y)));
        acc.z += (selu_f(fmaf(v0.z, c0.z, h0.z)) + selu_f(fmaf(v1.z, c1.z, h1.z)))
               + (selu_f(fmaf(v2.z, c2.z, h2.z)) + selu_f(fmaf(v3.z, c3.z, h3.z)));
        acc.w += (selu_f(fmaf(v0.w, c0.w, h0.w)) + selu_f(fmaf(v1.w, c1.w, h1.w)))
               + (selu_f(fmaf(v2.w, c2.w, h2.w)) + selu_f(fmaf(v3.w, c3.w, h3.w)));
    }
    for (; p < p1; p++){
        int s0 = colv[p];
        int g0 = batch[s0];
        float4 v0 = hv[(size_t)s0 * 32 + vo];
        float4 c0 = *reinterpret_cast<const float4*>(&scale[g0 * 128 + vo * 4]);
        float4 h0 = *reinterpret_cast<const float4*>(&shift[g0 * 128 + vo * 4]);
        acc.x += selu_f(fmaf(v0.x, c0.x, h0.x));
        acc.y += selu_f(fmaf(v0.y, c0.y, h0.y));
        acc.z += selu_f(fmaf(v0.z, c0.z, h0.z));
        acc.w += selu_f(fmaf(v0.w, c0.w, h0.w));
    }

    float vals[4] = {acc.x, acc.y, acc.z, acc.w};
    unsigned int h01, h23, l01, l23;
    {
        unsigned short hh[4], ll[4];
        #pragma unroll
        for (int j = 0; j < 4; j++){
            hh[j] = f2b(vals[j]);
            ll[j] = f2b(vals[j] - b2f(hh[j]));
        }
        h01 = (unsigned int)hh[0] | ((unsigned int)hh[1] << 16);
        h23 = (unsigned int)hh[2] | ((unsigned int)hh[3] << 16);
        l01 = (unsigned int)ll[0] | ((unsigned int)ll[1] << 16);
        l23 = (unsigned int)ll[2] | ((unsigned int)ll[3] << 16);
    }
    int kk = vo >> 3, kg = (vo >> 1) & 3, half = vo & 1;
    size_t fo = ((size_t)(i >> 4) * 4 + kk) * 512 + (kg * 16 + (i & 15)) * 8 + half * 4;
    *reinterpret_cast<uint2*>(zhi + fo) = make_uint2(h01, h23);
    *reinterpret_cast<uint2*>(zlo + fo) = make_uint2(l01, l23);
}

// ------- final-layer pool: transform raw z2 + pool, no store -------
__global__ __launch_bounds__(256) void pool_tx_kernel(
    const float* __restrict__ z2, const int* __restrict__ batch,
    const float* __restrict__ scale, const float* __restrict__ shift,
    float* __restrict__ pool, int l, int N)
{
    __shared__ int sb[128];
    int tid = threadIdx.x;
    int base = blockIdx.x * 128;
    int end = min(128, N - base);
    if (tid < 128) sb[tid] = (tid < end) ? batch[base + tid] : 0;
    __syncthreads();
    int vo = tid & 31;
    int r0 = (tid >> 5) * 16;
    if (r0 >= end) return;
    int rend = min(r0 + 16, end);
    const float4* zv = reinterpret_cast<const float4*>(z2);
    int run_g = sb[r0];
    float scx = scale[run_g * 128 + vo * 4 + 0], shx = shift[run_g * 128 + vo * 4 + 0];
    float scy = scale[run_g * 128 + vo * 4 + 1], shy = shift[run_g * 128 + vo * 4 + 1];
    float scz = scale[run_g * 128 + vo * 4 + 2], shz = shift[run_g * 128 + vo * 4 + 2];
    float scw = scale[run_g * 128 + vo * 4 + 3], shw = shift[run_g * 128 + vo * 4 + 3];
    float px = 0.f, py = 0.f, pz = 0.f, pw = 0.f;
    for (int r = r0; r < rend; r++){
        int g = sb[r];
        if (g != run_g){
            float* pp = &pool[run_g * 512 + l * 128 + vo * 4];
            atomicAdd(pp + 0, px); atomicAdd(pp + 1, py); atomicAdd(pp + 2, pz); atomicAdd(pp + 3, pw);
            px = py = pz = pw = 0.f;
            run_g = g;
            scx = scale[g * 128 + vo * 4 + 0]; shx = shift[g * 128 + vo * 4 + 0];
            scy = scale[g * 128 + vo * 4 + 1]; shy = shift[g * 128 + vo * 4 + 1];
            scz = scale[g * 128 + vo * 4 + 2]; shz = shift[g * 128 + vo * 4 + 2];
            scw = scale[g * 128 + vo * 4 + 3]; shw = shift[g * 128 + vo * 4 + 3];
        }
        size_t idx = (size_t)(base + r) * 32 + vo;
        float4 v = zv[idx];
        px += selu_f(fmaf(v.x, scx, shx));
        py += selu_f(fmaf(v.y, scy, shy));
        pz += selu_f(fmaf(v.z, scz, shz));
        pw += selu_f(fmaf(v.w, scw, shw));
    }
    float* pp = &pool[run_g * 512 + l * 128 + vo * 4];
    atomicAdd(pp + 0, px); atomicAdd(pp + 1, py); atomicAdd(pp + 2, pz); atomicAdd(pp + 3, pw);
}

// ------- transposed fragment read helper (row=feature, k=node) -------
__device__ __forceinline__ bf16x8 tread(const unsigned short* __restrict__ s, int base){
    union { bf16x8 v; unsigned short u[8]; } r;
    #pragma unroll
    for (int j = 0; j < 8; j++) r.u[j] = s[base + j * 8];
    return r.v;
}

// -------- moment pass: Mpart[blk] = partial z0^T z0, cpart = partial colsum --------
__global__ __launch_bounds__(256) void moment_k(
    const unsigned short* __restrict__ Zhi_g, const unsigned short* __restrict__ Zlo_g,
    float* __restrict__ Mpart, float* __restrict__ cpart, int RB)
{
    __shared__ __align__(16) unsigned short Zh_s[16384];   // 32 KB
    __shared__ __align__(16) unsigned short Zl_s[16384];   // 32 KB
    __shared__ float cs[256];
    int tid = threadIdx.x, lane = tid & 63, w = tid >> 6;
    int fl = lane & 15, g = lane >> 4;
    int tpart = (g >> 1) * 2048 + (g & 1) * 64;
    int fpart = (fl >> 3) * 128 + (fl & 7);

    f32x4 acc[2][8];
    #pragma unroll
    for (int i = 0; i < 2; i++)
        #pragma unroll
        for (int j = 0; j < 8; j++) acc[i][j] = (f32x4){0.f, 0.f, 0.f, 0.f};
    float csum = 0.f;
    int cf = tid & 127, chalf = tid >> 7;
    int cfbase = (cf >> 5) * 512 + ((cf >> 3) & 3) * 128 + (cf & 7);

    for (int blk = blockIdx.x; blk < RB; blk += MOMB){
        __syncthreads();
        {
            size_t gbase = (size_t)blk * 16384;
            const uint4* gh = reinterpret_cast<const uint4*>(Zhi_g + gbase);
            const uint4* gl = reinterpret_cast<const uint4*>(Zlo_g + gbase);
            uint4* sh4 = reinterpret_cast<uint4*>(Zh_s);
            uint4* sl4 = reinterpret_cast<uint4*>(Zl_s);
            #pragma unroll
            for (int j = 0; j < 8; j++){
                sh4[j * 256 + tid] = gh[j * 256 + tid];
                sl4[j * 256 + tid] = gl[j * 256 + tid];
            }
        }
        __syncthreads();

        #pragma unroll 8
        for (int n = chalf * 64; n < chalf * 64 + 64; n++){
            int addr = (n >> 4) * 2048 + (n & 15) * 8 + cfbase;
            csum += b2f(Zh_s[addr]) + b2f(Zl_s[addr]);
        }

        for (int nk = 0; nk < 4; nk++){
            int nb = nk * 4096 + tpart + fpart;
            bf16x8 ath[2], atl[2];
            #pragma unroll
            for (int i = 0; i < 2; i++){
                int ft = w * 2 + i;
                int base = nb + (ft >> 1) * 512 + (ft & 1) * 256;
                ath[i] = tread(Zh_s, base);
                atl[i] = tread(Zl_s, base);
            }
            #pragma unroll
            for (int ft2 = 0; ft2 < 8; ft2++){
                int base2 = nb + (ft2 >> 1) * 512 + (ft2 & 1) * 256;
                bf16x8 bth = tread(Zh_s, base2);
                bf16x8 btl = tread(Zl_s, base2);
                #pragma unroll
                for (int i = 0; i < 2; i++){
                    acc[i][ft2] = __builtin_amdgcn_mfma_f32_16x16x32_bf16(ath[i], bth, acc[i][ft2], 0, 0, 0);
                    acc[i][ft2] = __builtin_amdgcn_mfma_f32_16x16x32_bf16(ath[i], btl, acc[i][ft2], 0, 0, 0);
                    acc[i][ft2] = __builtin_amdgcn_mfma_f32_16x16x32_bf16(atl[i], bth, acc[i][ft2], 0, 0, 0);
                }
            }
        }
    }

    float* Mp = Mpart + (size_t)blockIdx.x * 16384;
    int col = lane & 15, rbase = (lane >> 4) * 4;
    #pragma unroll
    for (int i = 0; i < 2; i++)
        #pragma unroll
        for (int ft2 = 0; ft2 < 8; ft2++)
            #pragma unroll
            for (int r = 0; r < 4; r++){
                int a = (w * 2 + i) * 16 + rbase + r;
                int b = ft2 * 16 + col;
                Mp[a * 128 + b] = acc[i][ft2][r];
            }
    cs[tid] = csum;
    __syncthreads();
    if (tid < 128) cpart[(size_t)blockIdx.x * 128 + tid] = cs[tid] + cs[tid + 128];
}

// -------- reduce partials -> Msum (128x128), colsum (128) --------
__global__ __launch_bounds__(256) void reduce_k(
    const float* __restrict__ Mpart, const float* __restrict__ cpart,
    float* __restrict__ Msum, float* __restrict__ colsum)
{
    int gid = blockIdx.x * 256 + threadIdx.x;
    float s = 0.f;
    for (int p = 0; p < MOMB; p++) s += Mpart[(size_t)p * 16384 + gid];
    Msum[gid] = s;
    if (blockIdx.x == 0 && threadIdx.x < 128){
        float c = 0.f;
        for (int p = 0; p < MOMB; p++) c += cpart[(size_t)p * 128 + threadIdx.x];
        colsum[threadIdx.x] = c;
    }
}

// -------- BN finalize from moments: var_j = w^T M w / N - mu^2 --------
__global__ __launch_bounds__(128) void bn_final2_k(
    const float* __restrict__ Msum, const float* __restrict__ colsum,
    const float* __restrict__ W1, const float* __restrict__ bng,
    const float* __restrict__ bnb, float* __restrict__ sc, float* __restrict__ sh,
    int l, float invN)
{
    __shared__ float s_w[128];
    __shared__ float red[4];
    int j = blockIdx.x;
    int t = threadIdx.x;
    float wt = W1[(size_t)l * 65536 + (size_t)j * 128 + t];
    s_w[t] = wt;
    __syncthreads();
    float y = 0.f;
    #pragma unroll 4
    for (int k = 0; k < 128; k++) y = fmaf(Msum[t * 128 + k], s_w[k], y);
    float p = wt * y;
    float mc = wt * colsum[t];
    #pragma unroll
    for (int off = 32; off >= 1; off >>= 1){
        p += __shfl_xor(p, off, 64);
        mc += __shfl_xor(mc, off, 64);
    }
    int lane = t & 63, wv = t >> 6;
    if (lane == 0){ red[wv * 2] = p; red[wv * 2 + 1] = mc; }
    __syncthreads();
    if (t == 0){
        float e2 = (red[0] + red[2]) * invN;
        float mu = (red[1] + red[3]) * invN;
        float var = e2 - mu * mu;
        float inv = rsqrtf(var + 1e-5f);
        float gg = bng[l * 512 + j] * inv;
        sc[j] = gg;
        sh[j] = bnb[l * 512 + j] - mu * gg;
    }
}

// ------- fused (8 waves, 64-node tile, 2 blocks/CU): gemm1 swapped ->
//         b64 P-store -> gemm2 -> z2 + GraphNorm partials in epilogue. -------
__global__ __launch_bounds__(512, 4) void fused_k(
    const unsigned short* __restrict__ Zhi_g, const unsigned short* __restrict__ Zlo_g,
    const unsigned short* __restrict__ B1p, const unsigned short* __restrict__ B2p,
    float* __restrict__ Z, const float* __restrict__ bsc, const float* __restrict__ bsh,
    const float* __restrict__ b2l, const int* __restrict__ batch,
    float* __restrict__ gsum, float* __restrict__ gsq, int N)
{
    __shared__ __align__(16) unsigned short Zh_s[8192];    // 16 KB
    __shared__ __align__(16) unsigned short Zl_s[8192];    // 16 KB
    __shared__ __align__(16) unsigned short Ph[64][136];   // 17.4 KB
    __shared__ __align__(16) unsigned short Pl[64][136];
    __shared__ float s_sc[512], s_sh[512];
    __shared__ int s_b[64];
    int tid = threadIdx.x, lane = tid & 63, w = tid >> 6;
    int wr = w >> 2, wq = w & 3;                 // wr 0..1 (32-node strip)
    int r_lo = lane & 15, kg = lane >> 4;
    int m0 = blockIdx.x * 64;

    if (tid < 512){ s_sc[tid] = bsc[tid]; s_sh[tid] = bsh[tid]; }
    if (tid < 64) s_b[tid] = (m0 + tid < N) ? batch[m0 + tid] : -1;
    {
        size_t gbase = (size_t)(m0 >> 4) * 2048;   // 4 tiles x 2048 elems
        const uint4* gh = reinterpret_cast<const uint4*>(Zhi_g + gbase);
        const uint4* gl = reinterpret_cast<const uint4*>(Zlo_g + gbase);
        uint4* sh4 = reinterpret_cast<uint4*>(Zh_s);
        uint4* sl4 = reinterpret_cast<uint4*>(Zl_s);
        #pragma unroll
        for (int j = 0; j < 2; j++){
            sh4[j * 512 + tid] = gh[j * 512 + tid];
            sl4[j * 512 + tid] = gl[j * 512 + tid];
        }
    }
    __syncthreads();

    int wc = wq >> 1;
    f32x4 acc2[2][2];
    #pragma unroll
    for (int i = 0; i < 2; i++)
        #pragma unroll
        for (int j = 0; j < 2; j++) acc2[i][j] = (f32x4){0.f, 0.f, 0.f, 0.f};

    for (int c = 0; c < 4; c++){
        // ---- gemm1 swapped: acc1[mfp][nfp] = z1^T frags ----
        f32x4 acc1[2][2];
        #pragma unroll
        for (int i = 0; i < 2; i++)
            #pragma unroll
            for (int j = 0; j < 2; j++) acc1[i][j] = (f32x4){0.f, 0.f, 0.f, 0.f};

        const bf16x8* B1v = reinterpret_cast<const bf16x8*>(B1p) + (size_t)c * 4096;
        for (int kk = 0; kk < 4; kk++){
            bf16x8 awh[2], awl[2];
            #pragma unroll
            for (int mfp = 0; mfp < 2; mfp++){
                int colblk = wq * 2 + mfp;
                int wc1 = colblk >> 2, nf1 = colblk & 3;
                int ob = ((kk * 2 + wc1) * 4 + nf1) * 2;
                awh[mfp] = B1v[(ob + 0) * 64 + lane];
                awl[mfp] = B1v[(ob + 1) * 64 + lane];
            }
            bf16x8 bzh[2], bzl[2];
            #pragma unroll
            for (int nfp = 0; nfp < 2; nfp++){
                int so = ((wr * 2 + nfp) * 4 + kk) * 512 + lane * 8;
                bzh[nfp] = *reinterpret_cast<const bf16x8*>(&Zh_s[so]);
                bzl[nfp] = *reinterpret_cast<const bf16x8*>(&Zl_s[so]);
            }
            #pragma unroll
            for (int mfp = 0; mfp < 2; mfp++)
                #pragma unroll
                for (int nfp = 0; nfp < 2; nfp++){
                    acc1[mfp][nfp] = __builtin_amdgcn_mfma_f32_16x16x32_bf16(awh[mfp], bzh[nfp], acc1[mfp][nfp], 0, 0, 0);
                    acc1[mfp][nfp] = __builtin_amdgcn_mfma_f32_16x16x32_bf16(awh[mfp], bzl[nfp], acc1[mfp][nfp], 0, 0, 0);
                    acc1[mfp][nfp] = __builtin_amdgcn_mfma_f32_16x16x32_bf16(awl[mfp], bzh[nfp], acc1[mfp][nfp], 0, 0, 0);
                }
        }

        // ---- BN + SELU + split -> Ph/Pl via b64 stores ----
        __syncthreads();
        #pragma unroll
        for (int mfp = 0; mfp < 2; mfp++){
            int ckb = wq * 32 + mfp * 16 + kg * 4;
            float sc0 = s_sc[c * 128 + ckb + 0], sh0 = s_sh[c * 128 + ckb + 0];
            float sc1 = s_sc[c * 128 + ckb + 1], sh1 = s_sh[c * 128 + ckb + 1];
            float sc2 = s_sc[c * 128 + ckb + 2], sh2 = s_sh[c * 128 + ckb + 2];
            float sc3 = s_sc[c * 128 + ckb + 3], sh3 = s_sh[c * 128 + ckb + 3];
            #pragma unroll
            for (int nfp = 0; nfp < 2; nfp++){
                float t0 = selu_f(fmaf(acc1[mfp][nfp][0], sc0, sh0));
                float t1 = selu_f(fmaf(acc1[mfp][nfp][1], sc1, sh1));
                float t2 = selu_f(fmaf(acc1[mfp][nfp][2], sc2, sh2));
                float t3 = selu_f(fmaf(acc1[mfp][nfp][3], sc3, sh3));
                unsigned short h0 = f2b(t0), h1 = f2b(t1), h2 = f2b(t2), h3 = f2b(t3);
                unsigned short l0 = f2b(t0 - b2f(h0)), l1 = f2b(t1 - b2f(h1));
                unsigned short l2 = f2b(t2 - b2f(h2)), l3 = f2b(t3 - b2f(h3));
                int node = wr * 32 + nfp * 16 + r_lo;
                uint2 hv = make_uint2((unsigned int)h0 | ((unsigned int)h1 << 16),
                                      (unsigned int)h2 | ((unsigned int)h3 << 16));
                uint2 lv = make_uint2((unsigned int)l0 | ((unsigned int)l1 << 16),
                                      (unsigned int)l2 | ((unsigned int)l3 << 16));
                *reinterpret_cast<uint2*>(&Ph[node][ckb]) = hv;
                *reinterpret_cast<uint2*>(&Pl[node][ckb]) = lv;
            }
        }
        __syncthreads();

        // ---- gemm2 accumulate over this K slice ----
        const bf16x8* B2v = reinterpret_cast<const bf16x8*>(B2p);
        for (int kk2 = 0; kk2 < 4; kk2++){
            int kkf = c * 4 + kk2;
            bf16x8 bh[2], bl[2];
            #pragma unroll
            for (int nf = 0; nf < 2; nf++){
                int nfold = (wq & 1) * 2 + nf;
                int ob = ((kkf * 2 + wc) * 4 + nfold) * 2;
                bh[nf] = B2v[(ob + 0) * 64 + lane];
                bl[nf] = B2v[(ob + 1) * 64 + lane];
            }
            bf16x8 ah[2], alr[2];
            #pragma unroll
            for (int mf = 0; mf < 2; mf++){
                int ar = wr * 32 + mf * 16 + r_lo;
                ah[mf]  = *reinterpret_cast<const bf16x8*>(&Ph[ar][kk2 * 32 + kg * 8]);
                alr[mf] = *reinterpret_cast<const bf16x8*>(&Pl[ar][kk2 * 32 + kg * 8]);
            }
            #pragma unroll
            for (int mf = 0; mf < 2; mf++)
                #pragma unroll
                for (int nf = 0; nf < 2; nf++){
                    acc2[mf][nf] = __builtin_amdgcn_mfma_f32_16x16x32_bf16(ah[mf],  bh[nf], acc2[mf][nf], 0, 0, 0);
                    acc2[mf][nf] = __builtin_amdgcn_mfma_f32_16x16x32_bf16(ah[mf],  bl[nf], acc2[mf][nf], 0, 0, 0);
                    acc2[mf][nf] = __builtin_amdgcn_mfma_f32_16x16x32_bf16(alr[mf], bh[nf], acc2[mf][nf], 0, 0, 0);
                }
        }
    }

    // ---- epilogue: z2 = acc2 + b2, plus GraphNorm partial sums ----
    #pragma unroll
    for (int nf = 0; nf < 2; nf++){
        int col = wq * 32 + nf * 16 + r_lo;
        float bv = b2l[col];
        float s = 0.f, q = 0.f;
        int run_g = -2;
        #pragma unroll
        for (int mf = 0; mf < 2; mf++)
            #pragma unroll
            for (int r = 0; r < 4; r++){
                int row_l = wr * 32 + mf * 16 + kg * 4 + r;
                int row = m0 + row_l;
                if (row < N){
                    float v = bv + acc2[mf][nf][r];
                    Z[(size_t)row * 128 + col] = v;
                    int g = s_b[row_l];
                    if (g != run_g){
                        if (run_g >= 0){
                            atomicAdd(&gsum[run_g * 128 + col], s);
                            atomicAdd(&gsq[run_g * 128 + col], q);
                        }
                        s = 0.f; q = 0.f; run_g = g;
                    }
                    s += v; q += v * v;
                }
            }
        if (run_g >= 0){
            atomicAdd(&gsum[run_g * 128 + col], s);
            atomicAdd(&gsq[run_g * 128 + col], q);
        }
    }
}

__global__ void gn_final_kernel(float* __restrict__ gsum, float* __restrict__ gsq,
                                const float* __restrict__ cnt,
                                const float* __restrict__ gng, const float* __restrict__ gnb,
                                const float* __restrict__ gna,
                                float* __restrict__ scale, float* __restrict__ shift, int l){
    int g = blockIdx.x, c = threadIdx.x;
    int idx = g * 128 + c;
    float n = cnt[g];
    float m = gsum[idx] / n;
    float e2 = gsq[idx] / n;
    float a = gna[l * 128 + c];
    float var = e2 - (2.f * a - a * a) * m * m;
    float inv = rsqrtf(var + 1e-5f);
    float sc = gng[l * 128 + c] * inv;
    scale[idx] = sc;
    shift[idx] = gnb[l * 128 + c] - a * m * sc;
    gsum[idx] = 0.f;
    gsq[idx] = 0.f;
}

__global__ void final_kernel(const float* __restrict__ pool, const float* __restrict__ cnt,
                             float* __restrict__ out, int n){
    int i = blockIdx.x * 256 + threadIdx.x;
    if (i < n) out[i] = pool[i] / cnt[i >> 9];
}

extern "C" void kernel_launch(void* const* d_in, const int* in_sizes, int n_in,
                              void* d_out, int out_size, void* d_ws, size_t ws_size,
                              hipStream_t stream){
    const float* x    = (const float*)d_in[0];
    const float* W1   = (const float*)d_in[1];
    const float* bng  = (const float*)d_in[2];
    const float* bnb  = (const float*)d_in[3];
    const float* W2   = (const float*)d_in[4];
    const float* b2   = (const float*)d_in[5];
    const float* gng  = (const float*)d_in[6];
    const float* gnb  = (const float*)d_in[7];
    const float* gna  = (const float*)d_in[8];
    const int*   ei   = (const int*)d_in[9];
    const int*   batch= (const int*)d_in[10];
    int N = in_sizes[0] / 128;
    int E = in_sizes[9] / 2;
    float* out = (float*)d_out;
    int RB = (N + 127) / 128;
    int RB64 = (N + 63) / 64;

    char* ws = (char*)d_ws;
    size_t off = 0;
    auto alloc = [&](size_t bytes) -> char* {
        char* p = ws + off;
        off += (bytes + 255) & ~(size_t)255;
        return p;
    };
    unsigned short* z0hi = (unsigned short*)alloc((size_t)RB * 128 * 128 * 2);
    unsigned short* z0lo = (unsigned short*)alloc((size_t)RB * 128 * 128 * 2);
    float* z2     = (float*)alloc((size_t)N * 128 * 4);
    unsigned short* W1p = (unsigned short*)alloc(524288 * 2);
    unsigned short* W2p = (unsigned short*)alloc(524288 * 2);
    int*   row_ptr= (int*)alloc((size_t)(N + 1) * 4);
    int*   colv   = (int*)alloc((size_t)E * 4);
    int*   counts = (int*)alloc((size_t)N * 4);
    int*   fill   = (int*)alloc((size_t)N * 4);
    float* cnt_f  = (float*)alloc(256 * 4);
    float* Mpart  = (float*)alloc((size_t)MOMB * 16384 * 4);   // 32 MB
    float* cpart  = (float*)alloc((size_t)MOMB * 128 * 4);
    float* Msum   = (float*)alloc(16384 * 4);
    float* colsum = (float*)alloc(128 * 4);
    float* bn_sc  = (float*)alloc(512 * 4);
    float* bn_sh  = (float*)alloc(512 * 4);
    float* gn_sum = (float*)alloc(256 * 128 * 4);  // contiguous with gn_sq
    float* gn_sq  = (float*)alloc(256 * 128 * 4);
    float* gn_sc  = (float*)alloc(256 * 128 * 4);
    float* gn_sh  = (float*)alloc(256 * 128 * 4);
    float* pool   = (float*)alloc(256 * 512 * 4);
    (void)ws_size;

    hipMemsetAsync(counts, 0, (size_t)N * 4, stream);
    hipMemsetAsync(fill,   0, (size_t)N * 4, stream);
    hipMemsetAsync(gn_sum, 0, 2 * 256 * 128 * 4, stream);      // gn_sum + gn_sq
    hipMemsetAsync(pool,   0, 256 * 512 * 4, stream);
    {
        size_t tail_start = (size_t)(N >> 4) * 2048;
        size_t total      = (size_t)RB * 128 * 128;
        if (total > tail_start){
            size_t tail_bytes = (total - tail_start) * 2;
            hipMemsetAsync(z0hi + tail_start, 0, tail_bytes, stream);
            hipMemsetAsync(z0lo + tail_start, 0, tail_bytes, stream);
        }
    }

    pack_kernel<<<256, 256, 0, stream>>>(W1, W2, W1p, W2p);
    count_kernel<<<(E + 255) / 256, 256, 0, stream>>>(ei + E, counts, E);
    scan_kernel<<<1, 1024, 0, stream>>>(counts, row_ptr, N);
    fill_kernel<<<(E + 255) / 256, 256, 0, stream>>>(ei, row_ptr, fill, colv, E);
    cnt_bs_kernel<<<1, 256, 0, stream>>>(batch, cnt_f, N);

    float invN = 1.f / (float)N;
    for (int l = 0; l < 4; l++){
        if (l == 0)
            agg_split_kernel<<<(N + 7) / 8, 256, 0, stream>>>(x, row_ptr, colv,
                                                              z0hi, z0lo, N);
        else
            agg_tx_kernel<<<(N + 7) / 8, 256, 0, stream>>>(z2, row_ptr, colv, batch,
                                                           gn_sc, gn_sh, z0hi, z0lo,
                                                           pool, l - 1, N);
        moment_k<<<MOMB, 256, 0, stream>>>(z0hi, z0lo, Mpart, cpart, RB);
        reduce_k<<<64, 256, 0, stream>>>(Mpart, cpart, Msum, colsum);
        bn_final2_k<<<512, 128, 0, stream>>>(Msum, colsum, W1, bng, bnb,
                                             bn_sc, bn_sh, l, invN);
        fused_k<<<RB64, 512, 0, stream>>>(z0hi, z0lo, W1p + (size_t)l * 131072,
                                          W2p + (size_t)l * 131072, z2,
                                          bn_sc, bn_sh, b2 + l * 128,
                                          batch, gn_sum, gn_sq, N);
        gn_final_kernel<<<256, 128, 0, stream>>>(gn_sum, gn_sq, cnt_f, gng, gnb, gna,
                                                 gn_sc, gn_sh, l);
    }
    pool_tx_kernel<<<RB, 256, 0, stream>>>(z2, batch, gn_sc, gn_sh, pool, 3, N);
    final_kernel<<<(out_size + 255) / 256, 256, 0, stream>>>(pool, cnt_f, out, out_size);
}

// Round 19
// 1267.158 us; speedup vs baseline: 1.0485x; 1.0485x over previous
//
#include <hip/hip_runtime.h>
#include <hip/hip_bf16.h>

// GIN 4-layer forward, round 19: revert to r17 (best measured, 1269us).
// MOMB=256, agg_tx 2-deep. fused_k 64-tile/2-blocks-CU, GN-stats epilogue,
// moment-based BN, on-the-fly GN+SELU in gather, no h materialization.

typedef __attribute__((ext_vector_type(8))) short bf16x8;
typedef __attribute__((ext_vector_type(4))) float f32x4;

#define MOMB 256

__device__ __forceinline__ unsigned short f2b(float x){
    __hip_bfloat16 h = __float2bfloat16(x);
    return *reinterpret_cast<unsigned short*>(&h);
}
__device__ __forceinline__ float b2f(unsigned short u){
    __hip_bfloat16 h;
    *reinterpret_cast<unsigned short*>(&h) = u;
    return __bfloat162float(h);
}
__device__ __forceinline__ float selu_f(float x){
    const float sc = 1.0507009873554805f, al = 1.6732632423543772f;
    return x > 0.f ? sc * x : sc * al * (__expf(x) - 1.f);
}

// ---------------- CSR build ----------------
__global__ void count_kernel(const int* __restrict__ dst, int* __restrict__ counts, int E){
    int e = blockIdx.x * 256 + threadIdx.x;
    if (e < E) atomicAdd(&counts[dst[e]], 1);
}

__global__ void cnt_bs_kernel(const int* __restrict__ batch, float* __restrict__ cnt, int N){
    __shared__ int sb[257];
    int g = threadIdx.x;
    int lo = 0, hi = N;
    while (lo < hi){ int mid = (lo + hi) >> 1; if (batch[mid] < g) lo = mid + 1; else hi = mid; }
    sb[g] = lo;
    if (g == 0) sb[256] = N;
    __syncthreads();
    cnt[g] = fmaxf((float)(sb[g + 1] - sb[g]), 1.f);
}

__global__ __launch_bounds__(1024) void scan_kernel(const int* __restrict__ counts,
                                                    int* __restrict__ row_ptr, int N){
    __shared__ int wsum[16];
    __shared__ int wpre[16];
    __shared__ int s_total;
    __shared__ int s_running;
    int tid = threadIdx.x;
    int lane = tid & 63, wid = tid >> 6;
    if (tid == 0) s_running = 0;
    __syncthreads();
    for (int base = 0; base < N; base += 4096){
        int idx0 = base + tid * 4;
        int v[4];
        #pragma unroll
        for (int j = 0; j < 4; j++) v[j] = (idx0 + j < N) ? counts[idx0 + j] : 0;
        int tsum = v[0] + v[1] + v[2] + v[3];
        int x = tsum;
        #pragma unroll
        for (int off = 1; off < 64; off <<= 1){
            int y = __shfl_up(x, off, 64);
            if (lane >= off) x += y;
        }
        if (lane == 63) wsum[wid] = x;
        __syncthreads();
        if (wid == 0 && lane < 16){
            int w = wsum[lane];
            int xx = w;
            #pragma unroll
            for (int off = 1; off < 16; off <<= 1){
                int y = __shfl_up(xx, off, 64);
                if (lane >= off) xx += y;
            }
            wpre[lane] = xx - w;
            if (lane == 15) s_total = xx;
        }
        __syncthreads();
        int run = s_running + wpre[wid] + (x - tsum);
        #pragma unroll
        for (int j = 0; j < 4; j++){
            if (idx0 + j < N) row_ptr[idx0 + j] = run;
            run += v[j];
        }
        __syncthreads();
        if (tid == 0) s_running += s_total;
        __syncthreads();
    }
    if (tid == 0) row_ptr[N] = s_running;
}

__global__ void fill_kernel(const int* __restrict__ ei, const int* __restrict__ row_ptr,
                            int* __restrict__ fill, int* __restrict__ colv, int E){
    int e = blockIdx.x * 256 + threadIdx.x;
    if (e < E){
        int s = ei[e];
        int d = ei[E + e];
        int pos = atomicAdd(&fill[d], 1);
        colv[row_ptr[d] + pos] = s;
    }
}

// ------------- weight pre-pack: f32 -> bf16 hi/lo fragments -------------
__global__ void pack_kernel(const float* __restrict__ W1, const float* __restrict__ W2,
                            unsigned short* __restrict__ W1p, unsigned short* __restrict__ W2p){
    int t = blockIdx.x * 256 + threadIdx.x;   // 65536 total
    int which = t >> 15;
    int u = t & 32767;
    int lane = u & 63; u >>= 6;
    int nf = u & 3; u >>= 2;
    int wc = u & 1; u >>= 1;
    int kk = u & 3; u >>= 2;
    int c = u & 3; u >>= 2;
    int l = u;
    int col = wc * 64 + nf * 16 + (lane & 15);
    int kbase = kk * 32 + (lane >> 4) * 8;
    size_t ob = ((((((size_t)(l * 4 + c) * 4 + kk) * 2 + wc) * 4 + nf) * 2) * 512) + lane * 8;
    unsigned short* dst = which == 0 ? W1p : W2p;
    #pragma unroll
    for (int j = 0; j < 8; j++){
        int k = kbase + j;
        float wv = which == 0 ? W1[((size_t)(l * 512) + c * 128 + col) * 128 + k]
                              : W2[((size_t)(l * 128) + col) * 512 + c * 128 + k];
        unsigned short hi = f2b(wv);
        unsigned short lo = f2b(wv - b2f(hi));
        dst[ob + j] = hi;
        dst[ob + 512 + j] = lo;
    }
}

// ------- layer-0 aggregation (x input, no transform) -> z0 fragments -------
__global__ __launch_bounds__(256) void agg_split_kernel(
    const float* __restrict__ h, const int* __restrict__ row_ptr,
    const int* __restrict__ colv,
    unsigned short* __restrict__ zhi, unsigned short* __restrict__ zlo, int N)
{
    int t = blockIdx.x * 256 + threadIdx.x;
    int i = t >> 5;
    if (i >= N) return;
    int vo = (t & 31);
    const float4* hv = reinterpret_cast<const float4*>(h);
    int p0 = row_ptr[i], p1 = row_ptr[i + 1];
    float4 acc = hv[(size_t)i * 32 + vo];
    int p = p0;
    for (; p + 4 <= p1; p += 4){
        int s0 = colv[p], s1 = colv[p + 1], s2 = colv[p + 2], s3 = colv[p + 3];
        float4 a = hv[(size_t)s0 * 32 + vo];
        float4 b = hv[(size_t)s1 * 32 + vo];
        float4 c = hv[(size_t)s2 * 32 + vo];
        float4 d = hv[(size_t)s3 * 32 + vo];
        acc.x += (a.x + b.x) + (c.x + d.x);
        acc.y += (a.y + b.y) + (c.y + d.y);
        acc.z += (a.z + b.z) + (c.z + d.z);
        acc.w += (a.w + b.w) + (c.w + d.w);
    }
    for (; p < p1; p++){
        float4 a = hv[(size_t)colv[p] * 32 + vo];
        acc.x += a.x; acc.y += a.y; acc.z += a.z; acc.w += a.w;
    }
    float vals[4] = {acc.x, acc.y, acc.z, acc.w};
    unsigned int h01, h23, l01, l23;
    {
        unsigned short hh[4], ll[4];
        #pragma unroll
        for (int j = 0; j < 4; j++){
            hh[j] = f2b(vals[j]);
            ll[j] = f2b(vals[j] - b2f(hh[j]));
        }
        h01 = (unsigned int)hh[0] | ((unsigned int)hh[1] << 16);
        h23 = (unsigned int)hh[2] | ((unsigned int)hh[3] << 16);
        l01 = (unsigned int)ll[0] | ((unsigned int)ll[1] << 16);
        l23 = (unsigned int)ll[2] | ((unsigned int)ll[3] << 16);
    }
    int kk = vo >> 3, kg = (vo >> 1) & 3, half = vo & 1;
    size_t fo = ((size_t)(i >> 4) * 4 + kk) * 512 + (kg * 16 + (i & 15)) * 8 + half * 4;
    *reinterpret_cast<uint2*>(zhi + fo) = make_uint2(h01, h23);
    *reinterpret_cast<uint2*>(zlo + fo) = make_uint2(l01, l23);
}

// ------- layers 1..3 aggregation: gather raw z2, apply GN+SELU per row,
//         pool own-row values (block reduce), write z0 fragments -------
__global__ __launch_bounds__(256) void agg_tx_kernel(
    const float* __restrict__ z2, const int* __restrict__ row_ptr,
    const int* __restrict__ colv, const int* __restrict__ batch,
    const float* __restrict__ scale, const float* __restrict__ shift,
    unsigned short* __restrict__ zhi, unsigned short* __restrict__ zlo,
    float* __restrict__ pool, int lpool, int N)
{
    __shared__ float pbuf[8][128];
    __shared__ int s_g[8];
    int tid = threadIdx.x;
    int t = blockIdx.x * 256 + tid;
    int i = t >> 5;
    int vo = t & 31;
    int il = tid >> 5;
    if (vo == 0) s_g[il] = (i < N) ? batch[i] : -1;
    const float4* hv = reinterpret_cast<const float4*>(z2);
    float4 acc = make_float4(0.f, 0.f, 0.f, 0.f);
    if (i < N){
        int gi = batch[i];
        float4 v  = hv[(size_t)i * 32 + vo];
        float4 c4 = *reinterpret_cast<const float4*>(&scale[gi * 128 + vo * 4]);
        float4 s4 = *reinterpret_cast<const float4*>(&shift[gi * 128 + vo * 4]);
        acc.x = selu_f(fmaf(v.x, c4.x, s4.x));
        acc.y = selu_f(fmaf(v.y, c4.y, s4.y));
        acc.z = selu_f(fmaf(v.z, c4.z, s4.z));
        acc.w = selu_f(fmaf(v.w, c4.w, s4.w));
        pbuf[il][vo * 4 + 0] = acc.x;
        pbuf[il][vo * 4 + 1] = acc.y;
        pbuf[il][vo * 4 + 2] = acc.z;
        pbuf[il][vo * 4 + 3] = acc.w;
    }
    __syncthreads();
    if (tid < 128){
        float s = 0.f; int rg = -2;
        #pragma unroll
        for (int k = 0; k < 8; k++){
            int g = s_g[k];
            if (g < 0) continue;
            if (g != rg){
                if (rg >= 0) atomicAdd(&pool[rg * 512 + lpool * 128 + tid], s);
                s = 0.f; rg = g;
            }
            s += pbuf[k][tid];
        }
        if (rg >= 0) atomicAdd(&pool[rg * 512 + lpool * 128 + tid], s);
    }
    if (i >= N) return;

    int p0 = row_ptr[i], p1 = row_ptr[i + 1];
    int p = p0;
    for (; p + 2 <= p1; p += 2){
        int s0 = colv[p], s1 = colv[p + 1];
        int g0 = batch[s0], g1 = batch[s1];
        float4 v0 = hv[(size_t)s0 * 32 + vo];
        float4 v1 = hv[(size_t)s1 * 32 + vo];
        float4 c0 = *reinterpret_cast<const float4*>(&scale[g0 * 128 + vo * 4]);
        float4 h0 = *reinterpret_cast<const float4*>(&shift[g0 * 128 + vo * 4]);
        float4 c1 = *reinterpret_cast<const float4*>(&scale[g1 * 128 + vo * 4]);
        float4 h1 = *reinterpret_cast<const float4*>(&shift[g1 * 128 + vo * 4]);
        acc.x += selu_f(fmaf(v0.x, c0.x, h0.x)) + selu_f(fmaf(v1.x, c1.x, h1.x));
        acc.y += selu_f(fmaf(v0.y, c0.y, h0.y)) + selu_f(fmaf(v1.y, c1.y, h1.y));
        acc.z += selu_f(fmaf(v0.z, c0.z, h0.z)) + selu_f(fmaf(v1.z, c1.z, h1.z));
        acc.w += selu_f(fmaf(v0.w, c0.w, h0.w)) + selu_f(fmaf(v1.w, c1.w, h1.w));
    }
    for (; p < p1; p++){
        int s0 = colv[p];
        int g0 = batch[s0];
        float4 v0 = hv[(size_t)s0 * 32 + vo];
        float4 c0 = *reinterpret_cast<const float4*>(&scale[g0 * 128 + vo * 4]);
        float4 h0 = *reinterpret_cast<const float4*>(&shift[g0 * 128 + vo * 4]);
        acc.x += selu_f(fmaf(v0.x, c0.x, h0.x));
        acc.y += selu_f(fmaf(v0.y, c0.y, h0.y));
        acc.z += selu_f(fmaf(v0.z, c0.z, h0.z));
        acc.w += selu_f(fmaf(v0.w, c0.w, h0.w));
    }

    float vals[4] = {acc.x, acc.y, acc.z, acc.w};
    unsigned int h01, h23, l01, l23;
    {
        unsigned short hh[4], ll[4];
        #pragma unroll
        for (int j = 0; j < 4; j++){
            hh[j] = f2b(vals[j]);
            ll[j] = f2b(vals[j] - b2f(hh[j]));
        }
        h01 = (unsigned int)hh[0] | ((unsigned int)hh[1] << 16);
        h23 = (unsigned int)hh[2] | ((unsigned int)hh[3] << 16);
        l01 = (unsigned int)ll[0] | ((unsigned int)ll[1] << 16);
        l23 = (unsigned int)ll[2] | ((unsigned int)ll[3] << 16);
    }
    int kk = vo >> 3, kg = (vo >> 1) & 3, half = vo & 1;
    size_t fo = ((size_t)(i >> 4) * 4 + kk) * 512 + (kg * 16 + (i & 15)) * 8 + half * 4;
    *reinterpret_cast<uint2*>(zhi + fo) = make_uint2(h01, h23);
    *reinterpret_cast<uint2*>(zlo + fo) = make_uint2(l01, l23);
}

// ------- final-layer pool: transform raw z2 + pool, no store -------
__global__ __launch_bounds__(256) void pool_tx_kernel(
    const float* __restrict__ z2, const int* __restrict__ batch,
    const float* __restrict__ scale, const float* __restrict__ shift,
    float* __restrict__ pool, int l, int N)
{
    __shared__ int sb[128];
    int tid = threadIdx.x;
    int base = blockIdx.x * 128;
    int end = min(128, N - base);
    if (tid < 128) sb[tid] = (tid < end) ? batch[base + tid] : 0;
    __syncthreads();
    int vo = tid & 31;
    int r0 = (tid >> 5) * 16;
    if (r0 >= end) return;
    int rend = min(r0 + 16, end);
    const float4* zv = reinterpret_cast<const float4*>(z2);
    int run_g = sb[r0];
    float scx = scale[run_g * 128 + vo * 4 + 0], shx = shift[run_g * 128 + vo * 4 + 0];
    float scy = scale[run_g * 128 + vo * 4 + 1], shy = shift[run_g * 128 + vo * 4 + 1];
    float scz = scale[run_g * 128 + vo * 4 + 2], shz = shift[run_g * 128 + vo * 4 + 2];
    float scw = scale[run_g * 128 + vo * 4 + 3], shw = shift[run_g * 128 + vo * 4 + 3];
    float px = 0.f, py = 0.f, pz = 0.f, pw = 0.f;
    for (int r = r0; r < rend; r++){
        int g = sb[r];
        if (g != run_g){
            float* pp = &pool[run_g * 512 + l * 128 + vo * 4];
            atomicAdd(pp + 0, px); atomicAdd(pp + 1, py); atomicAdd(pp + 2, pz); atomicAdd(pp + 3, pw);
            px = py = pz = pw = 0.f;
            run_g = g;
            scx = scale[g * 128 + vo * 4 + 0]; shx = shift[g * 128 + vo * 4 + 0];
            scy = scale[g * 128 + vo * 4 + 1]; shy = shift[g * 128 + vo * 4 + 1];
            scz = scale[g * 128 + vo * 4 + 2]; shz = shift[g * 128 + vo * 4 + 2];
            scw = scale[g * 128 + vo * 4 + 3]; shw = shift[g * 128 + vo * 4 + 3];
        }
        size_t idx = (size_t)(base + r) * 32 + vo;
        float4 v = zv[idx];
        px += selu_f(fmaf(v.x, scx, shx));
        py += selu_f(fmaf(v.y, scy, shy));
        pz += selu_f(fmaf(v.z, scz, shz));
        pw += selu_f(fmaf(v.w, scw, shw));
    }
    float* pp = &pool[run_g * 512 + l * 128 + vo * 4];
    atomicAdd(pp + 0, px); atomicAdd(pp + 1, py); atomicAdd(pp + 2, pz); atomicAdd(pp + 3, pw);
}

// ------- transposed fragment read helper (row=feature, k=node) -------
__device__ __forceinline__ bf16x8 tread(const unsigned short* __restrict__ s, int base){
    union { bf16x8 v; unsigned short u[8]; } r;
    #pragma unroll
    for (int j = 0; j < 8; j++) r.u[j] = s[base + j * 8];
    return r.v;
}

// -------- moment pass: Mpart[blk] = partial z0^T z0, cpart = partial colsum --------
__global__ __launch_bounds__(256) void moment_k(
    const unsigned short* __restrict__ Zhi_g, const unsigned short* __restrict__ Zlo_g,
    float* __restrict__ Mpart, float* __restrict__ cpart, int RB)
{
    __shared__ __align__(16) unsigned short Zh_s[16384];   // 32 KB
    __shared__ __align__(16) unsigned short Zl_s[16384];   // 32 KB
    __shared__ float cs[256];
    int tid = threadIdx.x, lane = tid & 63, w = tid >> 6;
    int fl = lane & 15, g = lane >> 4;
    int tpart = (g >> 1) * 2048 + (g & 1) * 64;
    int fpart = (fl >> 3) * 128 + (fl & 7);

    f32x4 acc[2][8];
    #pragma unroll
    for (int i = 0; i < 2; i++)
        #pragma unroll
        for (int j = 0; j < 8; j++) acc[i][j] = (f32x4){0.f, 0.f, 0.f, 0.f};
    float csum = 0.f;
    int cf = tid & 127, chalf = tid >> 7;
    int cfbase = (cf >> 5) * 512 + ((cf >> 3) & 3) * 128 + (cf & 7);

    for (int blk = blockIdx.x; blk < RB; blk += MOMB){
        __syncthreads();
        {
            size_t gbase = (size_t)blk * 16384;
            const uint4* gh = reinterpret_cast<const uint4*>(Zhi_g + gbase);
            const uint4* gl = reinterpret_cast<const uint4*>(Zlo_g + gbase);
            uint4* sh4 = reinterpret_cast<uint4*>(Zh_s);
            uint4* sl4 = reinterpret_cast<uint4*>(Zl_s);
            #pragma unroll
            for (int j = 0; j < 8; j++){
                sh4[j * 256 + tid] = gh[j * 256 + tid];
                sl4[j * 256 + tid] = gl[j * 256 + tid];
            }
        }
        __syncthreads();

        #pragma unroll 8
        for (int n = chalf * 64; n < chalf * 64 + 64; n++){
            int addr = (n >> 4) * 2048 + (n & 15) * 8 + cfbase;
            csum += b2f(Zh_s[addr]) + b2f(Zl_s[addr]);
        }

        for (int nk = 0; nk < 4; nk++){
            int nb = nk * 4096 + tpart + fpart;
            bf16x8 ath[2], atl[2];
            #pragma unroll
            for (int i = 0; i < 2; i++){
                int ft = w * 2 + i;
                int base = nb + (ft >> 1) * 512 + (ft & 1) * 256;
                ath[i] = tread(Zh_s, base);
                atl[i] = tread(Zl_s, base);
            }
            #pragma unroll
            for (int ft2 = 0; ft2 < 8; ft2++){
                int base2 = nb + (ft2 >> 1) * 512 + (ft2 & 1) * 256;
                bf16x8 bth = tread(Zh_s, base2);
                bf16x8 btl = tread(Zl_s, base2);
                #pragma unroll
                for (int i = 0; i < 2; i++){
                    acc[i][ft2] = __builtin_amdgcn_mfma_f32_16x16x32_bf16(ath[i], bth, acc[i][ft2], 0, 0, 0);
                    acc[i][ft2] = __builtin_amdgcn_mfma_f32_16x16x32_bf16(ath[i], btl, acc[i][ft2], 0, 0, 0);
                    acc[i][ft2] = __builtin_amdgcn_mfma_f32_16x16x32_bf16(atl[i], bth, acc[i][ft2], 0, 0, 0);
                }
            }
        }
    }

    float* Mp = Mpart + (size_t)blockIdx.x * 16384;
    int col = lane & 15, rbase = (lane >> 4) * 4;
    #pragma unroll
    for (int i = 0; i < 2; i++)
        #pragma unroll
        for (int ft2 = 0; ft2 < 8; ft2++)
            #pragma unroll
            for (int r = 0; r < 4; r++){
                int a = (w * 2 + i) * 16 + rbase + r;
                int b = ft2 * 16 + col;
                Mp[a * 128 + b] = acc[i][ft2][r];
            }
    cs[tid] = csum;
    __syncthreads();
    if (tid < 128) cpart[(size_t)blockIdx.x * 128 + tid] = cs[tid] + cs[tid + 128];
}

// -------- reduce partials -> Msum (128x128), colsum (128) --------
__global__ __launch_bounds__(256) void reduce_k(
    const float* __restrict__ Mpart, const float* __restrict__ cpart,
    float* __restrict__ Msum, float* __restrict__ colsum)
{
    int gid = blockIdx.x * 256 + threadIdx.x;
    float s = 0.f;
    for (int p = 0; p < MOMB; p++) s += Mpart[(size_t)p * 16384 + gid];
    Msum[gid] = s;
    if (blockIdx.x == 0 && threadIdx.x < 128){
        float c = 0.f;
        for (int p = 0; p < MOMB; p++) c += cpart[(size_t)p * 128 + threadIdx.x];
        colsum[threadIdx.x] = c;
    }
}

// -------- BN finalize from moments: var_j = w^T M w / N - mu^2 --------
__global__ __launch_bounds__(128) void bn_final2_k(
    const float* __restrict__ Msum, const float* __restrict__ colsum,
    const float* __restrict__ W1, const float* __restrict__ bng,
    const float* __restrict__ bnb, float* __restrict__ sc, float* __restrict__ sh,
    int l, float invN)
{
    __shared__ float s_w[128];
    __shared__ float red[4];
    int j = blockIdx.x;
    int t = threadIdx.x;
    float wt = W1[(size_t)l * 65536 + (size_t)j * 128 + t];
    s_w[t] = wt;
    __syncthreads();
    float y = 0.f;
    #pragma unroll 4
    for (int k = 0; k < 128; k++) y = fmaf(Msum[t * 128 + k], s_w[k], y);
    float p = wt * y;
    float mc = wt * colsum[t];
    #pragma unroll
    for (int off = 32; off >= 1; off >>= 1){
        p += __shfl_xor(p, off, 64);
        mc += __shfl_xor(mc, off, 64);
    }
    int lane = t & 63, wv = t >> 6;
    if (lane == 0){ red[wv * 2] = p; red[wv * 2 + 1] = mc; }
    __syncthreads();
    if (t == 0){
        float e2 = (red[0] + red[2]) * invN;
        float mu = (red[1] + red[3]) * invN;
        float var = e2 - mu * mu;
        float inv = rsqrtf(var + 1e-5f);
        float gg = bng[l * 512 + j] * inv;
        sc[j] = gg;
        sh[j] = bnb[l * 512 + j] - mu * gg;
    }
}

// ------- fused (8 waves, 64-node tile, 2 blocks/CU): gemm1 swapped ->
//         b64 P-store -> gemm2 -> z2 + GraphNorm partials in epilogue. -------
__global__ __launch_bounds__(512, 4) void fused_k(
    const unsigned short* __restrict__ Zhi_g, const unsigned short* __restrict__ Zlo_g,
    const unsigned short* __restrict__ B1p, const unsigned short* __restrict__ B2p,
    float* __restrict__ Z, const float* __restrict__ bsc, const float* __restrict__ bsh,
    const float* __restrict__ b2l, const int* __restrict__ batch,
    float* __restrict__ gsum, float* __restrict__ gsq, int N)
{
    __shared__ __align__(16) unsigned short Zh_s[8192];    // 16 KB
    __shared__ __align__(16) unsigned short Zl_s[8192];    // 16 KB
    __shared__ __align__(16) unsigned short Ph[64][136];   // 17.4 KB
    __shared__ __align__(16) unsigned short Pl[64][136];
    __shared__ float s_sc[512], s_sh[512];
    __shared__ int s_b[64];
    int tid = threadIdx.x, lane = tid & 63, w = tid >> 6;
    int wr = w >> 2, wq = w & 3;                 // wr 0..1 (32-node strip)
    int r_lo = lane & 15, kg = lane >> 4;
    int m0 = blockIdx.x * 64;

    if (tid < 512){ s_sc[tid] = bsc[tid]; s_sh[tid] = bsh[tid]; }
    if (tid < 64) s_b[tid] = (m0 + tid < N) ? batch[m0 + tid] : -1;
    {
        size_t gbase = (size_t)(m0 >> 4) * 2048;   // 4 tiles x 2048 elems
        const uint4* gh = reinterpret_cast<const uint4*>(Zhi_g + gbase);
        const uint4* gl = reinterpret_cast<const uint4*>(Zlo_g + gbase);
        uint4* sh4 = reinterpret_cast<uint4*>(Zh_s);
        uint4* sl4 = reinterpret_cast<uint4*>(Zl_s);
        #pragma unroll
        for (int j = 0; j < 2; j++){
            sh4[j * 512 + tid] = gh[j * 512 + tid];
            sl4[j * 512 + tid] = gl[j * 512 + tid];
        }
    }
    __syncthreads();

    int wc = wq >> 1;
    f32x4 acc2[2][2];
    #pragma unroll
    for (int i = 0; i < 2; i++)
        #pragma unroll
        for (int j = 0; j < 2; j++) acc2[i][j] = (f32x4){0.f, 0.f, 0.f, 0.f};

    for (int c = 0; c < 4; c++){
        // ---- gemm1 swapped: acc1[mfp][nfp] = z1^T frags ----
        f32x4 acc1[2][2];
        #pragma unroll
        for (int i = 0; i < 2; i++)
            #pragma unroll
            for (int j = 0; j < 2; j++) acc1[i][j] = (f32x4){0.f, 0.f, 0.f, 0.f};

        const bf16x8* B1v = reinterpret_cast<const bf16x8*>(B1p) + (size_t)c * 4096;
        for (int kk = 0; kk < 4; kk++){
            bf16x8 awh[2], awl[2];
            #pragma unroll
            for (int mfp = 0; mfp < 2; mfp++){
                int colblk = wq * 2 + mfp;
                int wc1 = colblk >> 2, nf1 = colblk & 3;
                int ob = ((kk * 2 + wc1) * 4 + nf1) * 2;
                awh[mfp] = B1v[(ob + 0) * 64 + lane];
                awl[mfp] = B1v[(ob + 1) * 64 + lane];
            }
            bf16x8 bzh[2], bzl[2];
            #pragma unroll
            for (int nfp = 0; nfp < 2; nfp++){
                int so = ((wr * 2 + nfp) * 4 + kk) * 512 + lane * 8;
                bzh[nfp] = *reinterpret_cast<const bf16x8*>(&Zh_s[so]);
                bzl[nfp] = *reinterpret_cast<const bf16x8*>(&Zl_s[so]);
            }
            #pragma unroll
            for (int mfp = 0; mfp < 2; mfp++)
                #pragma unroll
                for (int nfp = 0; nfp < 2; nfp++){
                    acc1[mfp][nfp] = __builtin_amdgcn_mfma_f32_16x16x32_bf16(awh[mfp], bzh[nfp], acc1[mfp][nfp], 0, 0, 0);
                    acc1[mfp][nfp] = __builtin_amdgcn_mfma_f32_16x16x32_bf16(awh[mfp], bzl[nfp], acc1[mfp][nfp], 0, 0, 0);
                    acc1[mfp][nfp] = __builtin_amdgcn_mfma_f32_16x16x32_bf16(awl[mfp], bzh[nfp], acc1[mfp][nfp], 0, 0, 0);
                }
        }

        // ---- BN + SELU + split -> Ph/Pl via b64 stores ----
        __syncthreads();
        #pragma unroll
        for (int mfp = 0; mfp < 2; mfp++){
            int ckb = wq * 32 + mfp * 16 + kg * 4;
            float sc0 = s_sc[c * 128 + ckb + 0], sh0 = s_sh[c * 128 + ckb + 0];
            float sc1 = s_sc[c * 128 + ckb + 1], sh1 = s_sh[c * 128 + ckb + 1];
            float sc2 = s_sc[c * 128 + ckb + 2], sh2 = s_sh[c * 128 + ckb + 2];
            float sc3 = s_sc[c * 128 + ckb + 3], sh3 = s_sh[c * 128 + ckb + 3];
            #pragma unroll
            for (int nfp = 0; nfp < 2; nfp++){
                float t0 = selu_f(fmaf(acc1[mfp][nfp][0], sc0, sh0));
                float t1 = selu_f(fmaf(acc1[mfp][nfp][1], sc1, sh1));
                float t2 = selu_f(fmaf(acc1[mfp][nfp][2], sc2, sh2));
                float t3 = selu_f(fmaf(acc1[mfp][nfp][3], sc3, sh3));
                unsigned short h0 = f2b(t0), h1 = f2b(t1), h2 = f2b(t2), h3 = f2b(t3);
                unsigned short l0 = f2b(t0 - b2f(h0)), l1 = f2b(t1 - b2f(h1));
                unsigned short l2 = f2b(t2 - b2f(h2)), l3 = f2b(t3 - b2f(h3));
                int node = wr * 32 + nfp * 16 + r_lo;
                uint2 hv = make_uint2((unsigned int)h0 | ((unsigned int)h1 << 16),
                                      (unsigned int)h2 | ((unsigned int)h3 << 16));
                uint2 lv = make_uint2((unsigned int)l0 | ((unsigned int)l1 << 16),
                                      (unsigned int)l2 | ((unsigned int)l3 << 16));
                *reinterpret_cast<uint2*>(&Ph[node][ckb]) = hv;
                *reinterpret_cast<uint2*>(&Pl[node][ckb]) = lv;
            }
        }
        __syncthreads();

        // ---- gemm2 accumulate over this K slice ----
        const bf16x8* B2v = reinterpret_cast<const bf16x8*>(B2p);
        for (int kk2 = 0; kk2 < 4; kk2++){
            int kkf = c * 4 + kk2;
            bf16x8 bh[2], bl[2];
            #pragma unroll
            for (int nf = 0; nf < 2; nf++){
                int nfold = (wq & 1) * 2 + nf;
                int ob = ((kkf * 2 + wc) * 4 + nfold) * 2;
                bh[nf] = B2v[(ob + 0) * 64 + lane];
                bl[nf] = B2v[(ob + 1) * 64 + lane];
            }
            bf16x8 ah[2], alr[2];
            #pragma unroll
            for (int mf = 0; mf < 2; mf++){
                int ar = wr * 32 + mf * 16 + r_lo;
                ah[mf]  = *reinterpret_cast<const bf16x8*>(&Ph[ar][kk2 * 32 + kg * 8]);
                alr[mf] = *reinterpret_cast<const bf16x8*>(&Pl[ar][kk2 * 32 + kg * 8]);
            }
            #pragma unroll
            for (int mf = 0; mf < 2; mf++)
                #pragma unroll
                for (int nf = 0; nf < 2; nf++){
                    acc2[mf][nf] = __builtin_amdgcn_mfma_f32_16x16x32_bf16(ah[mf],  bh[nf], acc2[mf][nf], 0, 0, 0);
                    acc2[mf][nf] = __builtin_amdgcn_mfma_f32_16x16x32_bf16(ah[mf],  bl[nf], acc2[mf][nf], 0, 0, 0);
                    acc2[mf][nf] = __builtin_amdgcn_mfma_f32_16x16x32_bf16(alr[mf], bh[nf], acc2[mf][nf], 0, 0, 0);
                }
        }
    }

    // ---- epilogue: z2 = acc2 + b2, plus GraphNorm partial sums ----
    #pragma unroll
    for (int nf = 0; nf < 2; nf++){
        int col = wq * 32 + nf * 16 + r_lo;
        float bv = b2l[col];
        float s = 0.f, q = 0.f;
        int run_g = -2;
        #pragma unroll
        for (int mf = 0; mf < 2; mf++)
            #pragma unroll
            for (int r = 0; r < 4; r++){
                int row_l = wr * 32 + mf * 16 + kg * 4 + r;
                int row = m0 + row_l;
                if (row < N){
                    float v = bv + acc2[mf][nf][r];
                    Z[(size_t)row * 128 + col] = v;
                    int g = s_b[row_l];
                    if (g != run_g){
                        if (run_g >= 0){
                            atomicAdd(&gsum[run_g * 128 + col], s);
                            atomicAdd(&gsq[run_g * 128 + col], q);
                        }
                        s = 0.f; q = 0.f; run_g = g;
                    }
                    s += v; q += v * v;
                }
            }
        if (run_g >= 0){
            atomicAdd(&gsum[run_g * 128 + col], s);
            atomicAdd(&gsq[run_g * 128 + col], q);
        }
    }
}

__global__ void gn_final_kernel(float* __restrict__ gsum, float* __restrict__ gsq,
                                const float* __restrict__ cnt,
                                const float* __restrict__ gng, const float* __restrict__ gnb,
                                const float* __restrict__ gna,
                                float* __restrict__ scale, float* __restrict__ shift, int l){
    int g = blockIdx.x, c = threadIdx.x;
    int idx = g * 128 + c;
    float n = cnt[g];
    float m = gsum[idx] / n;
    float e2 = gsq[idx] / n;
    float a = gna[l * 128 + c];
    float var = e2 - (2.f * a - a * a) * m * m;
    float inv = rsqrtf(var + 1e-5f);
    float sc = gng[l * 128 + c] * inv;
    scale[idx] = sc;
    shift[idx] = gnb[l * 128 + c] - a * m * sc;
    gsum[idx] = 0.f;
    gsq[idx] = 0.f;
}

__global__ void final_kernel(const float* __restrict__ pool, const float* __restrict__ cnt,
                             float* __restrict__ out, int n){
    int i = blockIdx.x * 256 + threadIdx.x;
    if (i < n) out[i] = pool[i] / cnt[i >> 9];
}

extern "C" void kernel_launch(void* const* d_in, const int* in_sizes, int n_in,
                              void* d_out, int out_size, void* d_ws, size_t ws_size,
                              hipStream_t stream){
    const float* x    = (const float*)d_in[0];
    const float* W1   = (const float*)d_in[1];
    const float* bng  = (const float*)d_in[2];
    const float* bnb  = (const float*)d_in[3];
    const float* W2   = (const float*)d_in[4];
    const float* b2   = (const float*)d_in[5];
    const float* gng  = (const float*)d_in[6];
    const float* gnb  = (const float*)d_in[7];
    const float* gna  = (const float*)d_in[8];
    const int*   ei   = (const int*)d_in[9];
    const int*   batch= (const int*)d_in[10];
    int N = in_sizes[0] / 128;
    int E = in_sizes[9] / 2;
    float* out = (float*)d_out;
    int RB = (N + 127) / 128;
    int RB64 = (N + 63) / 64;

    char* ws = (char*)d_ws;
    size_t off = 0;
    auto alloc = [&](size_t bytes) -> char* {
        char* p = ws + off;
        off += (bytes + 255) & ~(size_t)255;
        return p;
    };
    unsigned short* z0hi = (unsigned short*)alloc((size_t)RB * 128 * 128 * 2);
    unsigned short* z0lo = (unsigned short*)alloc((size_t)RB * 128 * 128 * 2);
    float* z2     = (float*)alloc((size_t)N * 128 * 4);
    unsigned short* W1p = (unsigned short*)alloc(524288 * 2);
    unsigned short* W2p = (unsigned short*)alloc(524288 * 2);
    int*   row_ptr= (int*)alloc((size_t)(N + 1) * 4);
    int*   colv   = (int*)alloc((size_t)E * 4);
    int*   counts = (int*)alloc((size_t)N * 4);
    int*   fill   = (int*)alloc((size_t)N * 4);
    float* cnt_f  = (float*)alloc(256 * 4);
    float* Mpart  = (float*)alloc((size_t)MOMB * 16384 * 4);   // 16 MB
    float* cpart  = (float*)alloc((size_t)MOMB * 128 * 4);
    float* Msum   = (float*)alloc(16384 * 4);
    float* colsum = (float*)alloc(128 * 4);
    float* bn_sc  = (float*)alloc(512 * 4);
    float* bn_sh  = (float*)alloc(512 * 4);
    float* gn_sum = (float*)alloc(256 * 128 * 4);  // contiguous with gn_sq
    float* gn_sq  = (float*)alloc(256 * 128 * 4);
    float* gn_sc  = (float*)alloc(256 * 128 * 4);
    float* gn_sh  = (float*)alloc(256 * 128 * 4);
    float* pool   = (float*)alloc(256 * 512 * 4);
    (void)ws_size;

    hipMemsetAsync(counts, 0, (size_t)N * 4, stream);
    hipMemsetAsync(fill,   0, (size_t)N * 4, stream);
    hipMemsetAsync(gn_sum, 0, 2 * 256 * 128 * 4, stream);      // gn_sum + gn_sq
    hipMemsetAsync(pool,   0, 256 * 512 * 4, stream);
    {
        size_t tail_start = (size_t)(N >> 4) * 2048;
        size_t total      = (size_t)RB * 128 * 128;
        if (total > tail_start){
            size_t tail_bytes = (total - tail_start) * 2;
            hipMemsetAsync(z0hi + tail_start, 0, tail_bytes, stream);
            hipMemsetAsync(z0lo + tail_start, 0, tail_bytes, stream);
        }
    }

    pack_kernel<<<256, 256, 0, stream>>>(W1, W2, W1p, W2p);
    count_kernel<<<(E + 255) / 256, 256, 0, stream>>>(ei + E, counts, E);
    scan_kernel<<<1, 1024, 0, stream>>>(counts, row_ptr, N);
    fill_kernel<<<(E + 255) / 256, 256, 0, stream>>>(ei, row_ptr, fill, colv, E);
    cnt_bs_kernel<<<1, 256, 0, stream>>>(batch, cnt_f, N);

    float invN = 1.f / (float)N;
    for (int l = 0; l < 4; l++){
        if (l == 0)
            agg_split_kernel<<<(N + 7) / 8, 256, 0, stream>>>(x, row_ptr, colv,
                                                              z0hi, z0lo, N);
        else
            agg_tx_kernel<<<(N + 7) / 8, 256, 0, stream>>>(z2, row_ptr, colv, batch,
                                                           gn_sc, gn_sh, z0hi, z0lo,
                                                           pool, l - 1, N);
        moment_k<<<MOMB, 256, 0, stream>>>(z0hi, z0lo, Mpart, cpart, RB);
        reduce_k<<<64, 256, 0, stream>>>(Mpart, cpart, Msum, colsum);
        bn_final2_k<<<512, 128, 0, stream>>>(Msum, colsum, W1, bng, bnb,
                                             bn_sc, bn_sh, l, invN);
        fused_k<<<RB64, 512, 0, stream>>>(z0hi, z0lo, W1p + (size_t)l * 131072,
                                          W2p + (size_t)l * 131072, z2,
                                          bn_sc, bn_sh, b2 + l * 128,
                                          batch, gn_sum, gn_sq, N);
        gn_final_kernel<<<256, 128, 0, stream>>>(gn_sum, gn_sq, cnt_f, gng, gnb, gna,
                                                 gn_sc, gn_sh, l);
    }
    pool_tx_kernel<<<RB, 256, 0, stream>>>(z2, batch, gn_sc, gn_sh, pool, 3, N);
    final_kernel<<<(out_size + 255) / 256, 256, 0, stream>>>(pool, cnt_f, out, out_size);
}